// Round 6
// baseline (129.698 us; speedup 1.0000x reference)
//
#include <hip/hip_runtime.h>
#include <cstdint>

#define HEAT_THRESH 0.1f
#define STATIC_T 0.998f
#define WW 256
#define HH 256
#define TOPK 30
#define CAP 256            /* per-slice candidate capacity in ws */
#define NBINS 2048
#define CAP2 512
#define BASEBITS 0x3DCCCCCDu  /* float bits of 0.1f */
#define BINSH 14
#define MAXBIN 1740           /* ((0x3F800000 - BASEBITS) >> 14) */

typedef unsigned long long u64;

__device__ __forceinline__ u64 umax64(u64 a, u64 b) { return a > b ? a : b; }

// ---------------- Kernel 1: streaming NMS, batched loads for MLP ----------------
// Each wave owns an 8-row stripe; issues all 10 row loads (stripe+halos) up front.
__global__ __launch_bounds__(256, 6) void nms_scan(const float* __restrict__ heat,
                                                   u64* __restrict__ cand,
                                                   int* __restrict__ cnt) {
    const int blk = blockIdx.x;        // BC*8 blocks
    const int slice = blk >> 3;
    const int part = blk & 7;          // 32-row band within slice
    const float* __restrict__ hm = heat + (size_t)slice * (HH * WW);
    const int tid = threadIdx.x;
    const int lane = tid & 63;
    const int x0 = lane * 4;
    const int y0 = part * 32 + (tid >> 6) * 8;   // wave stripe: rows [y0, y0+8)
    const float NEG = -INFINITY;
    const float4 NEG4 = make_float4(NEG, NEG, NEG, NEG);

    auto ld = [&](int y) { return *reinterpret_cast<const float4*>(hm + y * WW + x0); };
    auto hmaxs = [&](const float4& v, float4& h) {
        float l = __shfl_up(v.w, 1u, 64);
        float r = __shfl_down(v.x, 1u, 64);
        if (lane == 0) l = NEG;
        if (lane == 63) r = NEG;
        h.x = fmaxf(fmaxf(l, v.x), v.y);
        h.y = fmaxf(fmaxf(v.x, v.y), v.z);
        h.z = fmaxf(fmaxf(v.y, v.z), v.w);
        h.w = fmaxf(fmaxf(v.z, v.w), r);
    };

    // batch-issue all 10 independent row loads (rows y0-1 .. y0+8)
    float4 r[10];
    #pragma unroll
    for (int j = 0; j < 10; ++j) {
        const int y = y0 - 1 + j;                 // wave-uniform bounds check
        r[j] = (y >= 0 && y < HH) ? ld(y) : NEG4;
    }

    // rolling horizontal-max trio; process row j after h[j+1] is ready
    float4 h0, h1, h2;
    hmaxs(r[0], h0);
    hmaxs(r[1], h1);
    #pragma unroll
    for (int t = 0; t < 8; ++t) {
        hmaxs(r[t + 2], h2);
        const float4 c = r[t + 1];
        const float va0 = fmaxf(fmaxf(h0.x, h1.x), h2.x);
        const float va1 = fmaxf(fmaxf(h0.y, h1.y), h2.y);
        const float va2 = fmaxf(fmaxf(h0.z, h1.z), h2.z);
        const float va3 = fmaxf(fmaxf(h0.w, h1.w), h2.w);
        const int ib = (y0 + t) * WW + x0;
        #define PUSH(cv, va, off)                                                           \
            if ((cv) == (va) && (cv) >= STATIC_T) {                                         \
                int p = atomicAdd(&cnt[slice], 1);                                          \
                if (p < CAP)                                                                \
                    cand[(size_t)slice * CAP + p] =                                         \
                        ((u64)__float_as_uint(cv) << 32) |                                  \
                        (u64)(0xFFFFu - (unsigned)(ib + (off)));                            \
            }
        PUSH(c.x, va0, 0)
        PUSH(c.y, va1, 1)
        PUSH(c.z, va2, 2)
        PUSH(c.w, va3, 3)
        #undef PUSH
        h0 = h1; h1 = h2;
    }
}

// ---------------- Kernel 2: per-slice top-30 selection (1 wave/slice) ----------------
__global__ __launch_bounds__(64, 8) void select_topk(const float* __restrict__ heat,
                                                     const u64* __restrict__ cand,
                                                     const int* __restrict__ cnt,
                                                     float* __restrict__ out, int BC) {
    const int slice = blockIdx.x;
    const int lane = threadIdx.x;
    const int n = cnt[slice];
    const float NEG = -INFINITY;
    const float4 NEG4 = make_float4(NEG, NEG, NEG, NEG);

    __shared__ unsigned hist[NBINS];
    __shared__ u64 c2[CAP2];
    __shared__ int cnt2_s;
    __shared__ unsigned tb_s;

    u64 loc[8];
    #pragma unroll
    for (int j = 0; j < 8; ++j) loc[j] = 0ull;

    if (n >= TOPK && n <= CAP) {
        // happy path: stored candidates are exactly all peaks >= STATIC_T, n >= 30 of them
        #pragma unroll
        for (int j = 0; j < 4; ++j) {
            const int i = lane + 64 * j;
            if (i < n) loc[j] = cand[(size_t)slice * CAP + i];
        }
    } else {
        // exact fallback (never taken for this distribution): full-slice 2-pass histogram
        const float* __restrict__ hm = heat + (size_t)slice * (HH * WW);
        const int x0 = lane * 4;
        auto ld = [&](int y) { return *reinterpret_cast<const float4*>(hm + y * WW + x0); };
        auto hmaxs = [&](const float4& v, float4& h) {
            float l = __shfl_up(v.w, 1u, 64);
            float r = __shfl_down(v.x, 1u, 64);
            if (lane == 0) l = NEG;
            if (lane == 63) r = NEG;
            h.x = fmaxf(fmaxf(l, v.x), v.y);
            h.y = fmaxf(fmaxf(v.x, v.y), v.z);
            h.z = fmaxf(fmaxf(v.y, v.z), v.w);
            h.w = fmaxf(fmaxf(v.z, v.w), r);
        };
        for (int i = lane; i < NBINS; i += 64) hist[i] = 0u;
        if (lane == 0) cnt2_s = 0;
        __syncthreads();
        // pass A: histogram of all peaks > thresh
        {
            float4 hmA = NEG4, hmB, cB, vN;
            cB = ld(0); hmaxs(cB, hmB);
            vN = ld(1);
            for (int y = 0; y < HH; ++y) {
                float4 hmC; hmaxs(vN, hmC);
                const float4 vNN = (y + 2 < HH) ? ld(y + 2) : NEG4;
                const float va0 = fmaxf(fmaxf(hmA.x, hmB.x), hmC.x);
                const float va1 = fmaxf(fmaxf(hmA.y, hmB.y), hmC.y);
                const float va2 = fmaxf(fmaxf(hmA.z, hmB.z), hmC.z);
                const float va3 = fmaxf(fmaxf(hmA.w, hmB.w), hmC.w);
                if (cB.x == va0 && cB.x > HEAT_THRESH) atomicAdd(&hist[(__float_as_uint(cB.x) - BASEBITS) >> BINSH], 1u);
                if (cB.y == va1 && cB.y > HEAT_THRESH) atomicAdd(&hist[(__float_as_uint(cB.y) - BASEBITS) >> BINSH], 1u);
                if (cB.z == va2 && cB.z > HEAT_THRESH) atomicAdd(&hist[(__float_as_uint(cB.z) - BASEBITS) >> BINSH], 1u);
                if (cB.w == va3 && cB.w > HEAT_THRESH) atomicAdd(&hist[(__float_as_uint(cB.w) - BASEBITS) >> BINSH], 1u);
                hmA = hmB; hmB = hmC; cB = vN; vN = vNN;
            }
        }
        __syncthreads();
        if (lane == 0) {
            unsigned cum = 0; int b;
            for (b = MAXBIN; b >= 0; --b) { cum += hist[b]; if (cum >= TOPK) break; }
            if (b < 0) b = 0;
            tb_s = BASEBITS + ((unsigned)b << BINSH);
        }
        __syncthreads();
        const unsigned tb = tb_s;
        // pass B: collect peaks >= tb
        {
            float4 hmA = NEG4, hmB, cB, vN;
            cB = ld(0); hmaxs(cB, hmB);
            vN = ld(1);
            for (int y = 0; y < HH; ++y) {
                float4 hmC; hmaxs(vN, hmC);
                const float4 vNN = (y + 2 < HH) ? ld(y + 2) : NEG4;
                const float va0 = fmaxf(fmaxf(hmA.x, hmB.x), hmC.x);
                const float va1 = fmaxf(fmaxf(hmA.y, hmB.y), hmC.y);
                const float va2 = fmaxf(fmaxf(hmA.z, hmB.z), hmC.z);
                const float va3 = fmaxf(fmaxf(hmA.w, hmB.w), hmC.w);
                const int ib = y * WW + x0;
                #define PUSHF(c, va, off)                                                   \
                    if ((c) == (va) && (c) > HEAT_THRESH && __float_as_uint(c) >= tb) {     \
                        int p = atomicAdd(&cnt2_s, 1);                                      \
                        if (p < CAP2)                                                       \
                            c2[p] = ((u64)__float_as_uint(c) << 32) |                       \
                                    (u64)(0xFFFFu - (unsigned)(ib + (off)));                \
                    }
                PUSHF(cB.x, va0, 0)
                PUSHF(cB.y, va1, 1)
                PUSHF(cB.z, va2, 2)
                PUSHF(cB.w, va3, 3)
                #undef PUSHF
                hmA = hmB; hmB = hmC; cB = vN; vN = vNN;
            }
        }
        __syncthreads();
        const int n2 = min(cnt2_s, CAP2);
        #pragma unroll
        for (int j = 0; j < 8; ++j) {
            const int i = lane + 64 * j;
            if (i < n2) loc[j] = c2[i];
        }
    }

    // ---- top-30 via butterfly argmax over per-lane registers ----
    u64 lmax = 0ull;
    #pragma unroll
    for (int j = 0; j < 8; ++j) lmax = umax64(lmax, loc[j]);

    for (int k = 0; k < TOPK; ++k) {
        u64 wm = lmax;
        #pragma unroll
        for (int s = 32; s; s >>= 1)
            wm = umax64(wm, (u64)__shfl_xor((long long)wm, s, 64));
        if (lane == 0) {
            const size_t bk = (size_t)slice * TOPK + k;
            const size_t nbk = (size_t)BC * TOPK;
            if (wm != 0ull) {
                const unsigned fb = (unsigned)(wm >> 32);
                const unsigned idx = 0xFFFFu - (unsigned)(wm & 0xFFFFFFFFull);
                out[bk * 2]       = (float)((idx & 255) * 4);
                out[bk * 2 + 1]   = (float)((idx >> 8) * 4);
                out[nbk * 2 + bk] = __uint_as_float(fb);
                out[nbk * 3 + bk] = 1.0f;
            } else {
                out[bk * 2] = 0.0f; out[bk * 2 + 1] = 0.0f;
                out[nbk * 2 + bk] = 0.0f; out[nbk * 3 + bk] = 0.0f;
            }
        }
        if (wm != 0ull && lmax == wm) {
            u64 nl = 0ull;
            #pragma unroll
            for (int j = 0; j < 8; ++j) {
                if (loc[j] == wm) loc[j] = 0ull;
                nl = umax64(nl, loc[j]);
            }
            lmax = nl;
        }
    }
}

extern "C" void kernel_launch(void* const* d_in, const int* in_sizes, int n_in,
                              void* d_out, int out_size, void* d_ws, size_t ws_size,
                              hipStream_t stream) {
    const float* heat = (const float*)d_in[0];
    float* out = (float*)d_out;
    const int BC = in_sizes[0] / (HH * WW);
    u64* cand = (u64*)d_ws;
    int* cnt = (int*)((char*)d_ws + (size_t)BC * CAP * sizeof(u64));
    hipMemsetAsync(cnt, 0, (size_t)BC * sizeof(int), stream);
    hipLaunchKernelGGL(nms_scan, dim3(BC * 8), dim3(256), 0, stream, heat, cand, cnt);
    hipLaunchKernelGGL(select_topk, dim3(BC), dim3(64), 0, stream, heat, cand, cnt, out, BC);
}

// Round 7
// 50.006 us; speedup vs baseline: 2.5936x; 2.5936x over previous
//
#include <hip/hip_runtime.h>
#include <cstdint>

#define HEAT_THRESH 0.1f
#define STATIC_T 0.998f
#define WW 256
#define HH 256
#define TOPK 30
#define CAPQ 128           /* per-quarter-slice candidate capacity */
#define NBINS 2048
#define CAP2 512
#define BASEBITS 0x3DCCCCCDu  /* float bits of 0.1f */
#define BINSH 14
#define MAXBIN 1740           /* ((0x3F800000 - BASEBITS) >> 14) */

typedef unsigned long long u64;

__device__ __forceinline__ u64 umax64(u64 a, u64 b) { return a > b ? a : b; }

// ---------------- Kernel 1: streaming NMS, LDS-only hot loop ----------------
// Quarter-slice per block (64 rows), 4 waves x 16-row stripes, rolling window.
// Candidates >= STATIC_T -> LDS list (LDS atomic); one coalesced global flush
// at block end. NO global atomics anywhere.
__global__ __launch_bounds__(256, 8) void nms_scan(const float* __restrict__ heat,
                                                   u64* __restrict__ cand,
                                                   int* __restrict__ cntq) {
    const int blk = blockIdx.x;        // BC*4 blocks
    const int slice = blk >> 2;
    const int q = blk & 3;
    const float* __restrict__ hm = heat + (size_t)slice * (HH * WW);
    const int tid = threadIdx.x;
    const int lane = tid & 63;
    const int x0 = lane * 4;
    const int y0 = q * 64 + (tid >> 6) * 16;     // wave stripe: rows [y0, y0+16)
    const float NEG = -INFINITY;
    const float4 NEG4 = make_float4(NEG, NEG, NEG, NEG);

    __shared__ u64 cl[CAPQ];
    __shared__ int lcnt;
    if (tid == 0) lcnt = 0;
    __syncthreads();

    auto ld = [&](int y) { return *reinterpret_cast<const float4*>(hm + y * WW + x0); };
    auto hmaxs = [&](const float4& v, float4& h) {
        float l = __shfl_up(v.w, 1u, 64);
        float r = __shfl_down(v.x, 1u, 64);
        if (lane == 0) l = NEG;
        if (lane == 63) r = NEG;
        h.x = fmaxf(fmaxf(l, v.x), v.y);
        h.y = fmaxf(fmaxf(v.x, v.y), v.z);
        h.z = fmaxf(fmaxf(v.y, v.z), v.w);
        h.w = fmaxf(fmaxf(v.z, v.w), r);
    };

    {
        float4 hmA, hmB, cB, vN;
        if (y0 > 0) { float4 v = ld(y0 - 1); hmaxs(v, hmA); }
        else hmA = NEG4;
        cB = ld(y0); hmaxs(cB, hmB);
        vN = (y0 + 1 < HH) ? ld(y0 + 1) : NEG4;

        #pragma unroll
        for (int t = 0; t < 16; ++t) {
            const int y = y0 + t;
            const float4 vNN = (t < 15 && y + 2 < HH) ? ld(y + 2) : NEG4;
            float4 hmC; hmaxs(vN, hmC);
            const float va0 = fmaxf(fmaxf(hmA.x, hmB.x), hmC.x);
            const float va1 = fmaxf(fmaxf(hmA.y, hmB.y), hmC.y);
            const float va2 = fmaxf(fmaxf(hmA.z, hmB.z), hmC.z);
            const float va3 = fmaxf(fmaxf(hmA.w, hmB.w), hmC.w);
            const int ib = y * WW + x0;
            #define PUSH(cv, va, off)                                                       \
                if ((cv) == (va) && (cv) >= STATIC_T) {                                     \
                    int p = atomicAdd(&lcnt, 1);                                            \
                    if (p < CAPQ)                                                           \
                        cl[p] = ((u64)__float_as_uint(cv) << 32) |                          \
                                (u64)(0xFFFFu - (unsigned)(ib + (off)));                    \
                }
            PUSH(cB.x, va0, 0)
            PUSH(cB.y, va1, 1)
            PUSH(cB.z, va2, 2)
            PUSH(cB.w, va3, 3)
            #undef PUSH
            hmA = hmB; hmB = hmC; cB = vN; vN = vNN;
        }
    }
    __syncthreads();

    // coalesced flush: count + candidate list (plain stores, no atomics)
    const int n = lcnt;
    if (tid == 0) cntq[blk] = n;
    const int nf = min(n, CAPQ);
    for (int i = tid; i < nf; i += 256) cand[(size_t)blk * CAPQ + i] = cl[i];
}

// ---------------- Kernel 2: per-slice top-30 selection (1 wave/slice) ----------------
__global__ __launch_bounds__(64, 8) void select_topk(const float* __restrict__ heat,
                                                     const u64* __restrict__ cand,
                                                     const int* __restrict__ cntq,
                                                     float* __restrict__ out, int BC) {
    const int slice = blockIdx.x;
    const int lane = threadIdx.x;
    const float NEG = -INFINITY;
    const float4 NEG4 = make_float4(NEG, NEG, NEG, NEG);

    __shared__ unsigned hist[NBINS];
    __shared__ u64 c2[CAP2];
    __shared__ int cnt2_s;
    __shared__ unsigned tb_s;

    const int n0 = cntq[slice * 4 + 0];
    const int n1 = cntq[slice * 4 + 1];
    const int n2 = cntq[slice * 4 + 2];
    const int n3 = cntq[slice * 4 + 3];
    const bool ok = (n0 <= CAPQ) && (n1 <= CAPQ) && (n2 <= CAPQ) && (n3 <= CAPQ) &&
                    (n0 + n1 + n2 + n3 >= TOPK);

    u64 loc[8];
    #pragma unroll
    for (int j = 0; j < 8; ++j) loc[j] = 0ull;

    if (ok) {
        // happy path: all peaks >= STATIC_T are in the 4 quarter lists; >= 30 total
        const int nq[4] = {n0, n1, n2, n3};
        #pragma unroll
        for (int qq = 0; qq < 4; ++qq) {
            const u64* src = cand + (size_t)(slice * 4 + qq) * CAPQ;
            if (lane < nq[qq])      loc[2 * qq]     = src[lane];
            if (lane + 64 < nq[qq]) loc[2 * qq + 1] = src[lane + 64];
        }
    } else {
        // exact fallback (never taken for this distribution): full-slice 2-pass histogram
        const float* __restrict__ hm = heat + (size_t)slice * (HH * WW);
        const int x0 = lane * 4;
        auto ld = [&](int y) { return *reinterpret_cast<const float4*>(hm + y * WW + x0); };
        auto hmaxs = [&](const float4& v, float4& h) {
            float l = __shfl_up(v.w, 1u, 64);
            float r = __shfl_down(v.x, 1u, 64);
            if (lane == 0) l = NEG;
            if (lane == 63) r = NEG;
            h.x = fmaxf(fmaxf(l, v.x), v.y);
            h.y = fmaxf(fmaxf(v.x, v.y), v.z);
            h.z = fmaxf(fmaxf(v.y, v.z), v.w);
            h.w = fmaxf(fmaxf(v.z, v.w), r);
        };
        for (int i = lane; i < NBINS; i += 64) hist[i] = 0u;
        if (lane == 0) cnt2_s = 0;
        __syncthreads();
        {
            float4 hmA = NEG4, hmB, cB, vN;
            cB = ld(0); hmaxs(cB, hmB);
            vN = ld(1);
            for (int y = 0; y < HH; ++y) {
                float4 hmC; hmaxs(vN, hmC);
                const float4 vNN = (y + 2 < HH) ? ld(y + 2) : NEG4;
                const float va0 = fmaxf(fmaxf(hmA.x, hmB.x), hmC.x);
                const float va1 = fmaxf(fmaxf(hmA.y, hmB.y), hmC.y);
                const float va2 = fmaxf(fmaxf(hmA.z, hmB.z), hmC.z);
                const float va3 = fmaxf(fmaxf(hmA.w, hmB.w), hmC.w);
                if (cB.x == va0 && cB.x > HEAT_THRESH) atomicAdd(&hist[(__float_as_uint(cB.x) - BASEBITS) >> BINSH], 1u);
                if (cB.y == va1 && cB.y > HEAT_THRESH) atomicAdd(&hist[(__float_as_uint(cB.y) - BASEBITS) >> BINSH], 1u);
                if (cB.z == va2 && cB.z > HEAT_THRESH) atomicAdd(&hist[(__float_as_uint(cB.z) - BASEBITS) >> BINSH], 1u);
                if (cB.w == va3 && cB.w > HEAT_THRESH) atomicAdd(&hist[(__float_as_uint(cB.w) - BASEBITS) >> BINSH], 1u);
                hmA = hmB; hmB = hmC; cB = vN; vN = vNN;
            }
        }
        __syncthreads();
        if (lane == 0) {
            unsigned cum = 0; int b;
            for (b = MAXBIN; b >= 0; --b) { cum += hist[b]; if (cum >= TOPK) break; }
            if (b < 0) b = 0;
            tb_s = BASEBITS + ((unsigned)b << BINSH);
        }
        __syncthreads();
        const unsigned tb = tb_s;
        {
            float4 hmA = NEG4, hmB, cB, vN;
            cB = ld(0); hmaxs(cB, hmB);
            vN = ld(1);
            for (int y = 0; y < HH; ++y) {
                float4 hmC; hmaxs(vN, hmC);
                const float4 vNN = (y + 2 < HH) ? ld(y + 2) : NEG4;
                const float va0 = fmaxf(fmaxf(hmA.x, hmB.x), hmC.x);
                const float va1 = fmaxf(fmaxf(hmA.y, hmB.y), hmC.y);
                const float va2 = fmaxf(fmaxf(hmA.z, hmB.z), hmC.z);
                const float va3 = fmaxf(fmaxf(hmA.w, hmB.w), hmC.w);
                const int ib = y * WW + x0;
                #define PUSHF(c, va, off)                                                   \
                    if ((c) == (va) && (c) > HEAT_THRESH && __float_as_uint(c) >= tb) {     \
                        int p = atomicAdd(&cnt2_s, 1);                                      \
                        if (p < CAP2)                                                       \
                            c2[p] = ((u64)__float_as_uint(c) << 32) |                       \
                                    (u64)(0xFFFFu - (unsigned)(ib + (off)));                \
                    }
                PUSHF(cB.x, va0, 0)
                PUSHF(cB.y, va1, 1)
                PUSHF(cB.z, va2, 2)
                PUSHF(cB.w, va3, 3)
                #undef PUSHF
                hmA = hmB; hmB = hmC; cB = vN; vN = vNN;
            }
        }
        __syncthreads();
        const int nn = min(cnt2_s, CAP2);
        #pragma unroll
        for (int j = 0; j < 8; ++j) {
            const int i = lane + 64 * j;
            if (i < nn) loc[j] = c2[i];
        }
    }

    // ---- top-30 via butterfly argmax over per-lane registers ----
    u64 lmax = 0ull;
    #pragma unroll
    for (int j = 0; j < 8; ++j) lmax = umax64(lmax, loc[j]);

    for (int k = 0; k < TOPK; ++k) {
        u64 wm = lmax;
        #pragma unroll
        for (int s = 32; s; s >>= 1)
            wm = umax64(wm, (u64)__shfl_xor((long long)wm, s, 64));
        if (lane == 0) {
            const size_t bk = (size_t)slice * TOPK + k;
            const size_t nbk = (size_t)BC * TOPK;
            if (wm != 0ull) {
                const unsigned fb = (unsigned)(wm >> 32);
                const unsigned idx = 0xFFFFu - (unsigned)(wm & 0xFFFFFFFFull);
                out[bk * 2]       = (float)((idx & 255) * 4);
                out[bk * 2 + 1]   = (float)((idx >> 8) * 4);
                out[nbk * 2 + bk] = __uint_as_float(fb);
                out[nbk * 3 + bk] = 1.0f;
            } else {
                out[bk * 2] = 0.0f; out[bk * 2 + 1] = 0.0f;
                out[nbk * 2 + bk] = 0.0f; out[nbk * 3 + bk] = 0.0f;
            }
        }
        if (wm != 0ull && lmax == wm) {
            u64 nl = 0ull;
            #pragma unroll
            for (int j = 0; j < 8; ++j) {
                if (loc[j] == wm) loc[j] = 0ull;
                nl = umax64(nl, loc[j]);
            }
            lmax = nl;
        }
    }
}

extern "C" void kernel_launch(void* const* d_in, const int* in_sizes, int n_in,
                              void* d_out, int out_size, void* d_ws, size_t ws_size,
                              hipStream_t stream) {
    const float* heat = (const float*)d_in[0];
    float* out = (float*)d_out;
    const int BC = in_sizes[0] / (HH * WW);
    u64* cand = (u64*)d_ws;
    int* cntq = (int*)((char*)d_ws + (size_t)BC * 4 * CAPQ * sizeof(u64));
    hipLaunchKernelGGL(nms_scan, dim3(BC * 4), dim3(256), 0, stream, heat, cand, cntq);
    hipLaunchKernelGGL(select_topk, dim3(BC), dim3(64), 0, stream, heat, cand, cntq, out, BC);
}

// Round 8
// 47.728 us; speedup vs baseline: 2.7174x; 1.0477x over previous
//
#include <hip/hip_runtime.h>
#include <cstdint>

#define HEAT_THRESH 0.1f
#define STATIC_T 0.998f
#define WW 256
#define HH 256
#define TOPK 30
#define CAPQ 128           /* per-quarter-slice candidate capacity */
#define NBINS 2048
#define CAP2 512
#define BASEBITS 0x3DCCCCCDu  /* float bits of 0.1f */
#define BINSH 14
#define MAXBIN 1740           /* ((0x3F800000 - BASEBITS) >> 14) */

typedef unsigned long long u64;

__device__ __forceinline__ u64 umax64(u64 a, u64 b) { return a > b ? a : b; }

// ---------------- Kernel 1: streaming NMS, batched-18 loads, LDS-only hot loop ----------------
// Quarter-slice per block (64 rows), 4 waves x 16-row stripes. All 18 row loads
// (stripe + 2 halos) issued unconditionally up front (clamped addresses), pinned
// by sched_barrier so the compiler cannot sink them -> ~18-deep MLP per wave.
__global__ __launch_bounds__(256, 4) void nms_scan(const float* __restrict__ heat,
                                                   u64* __restrict__ cand,
                                                   int* __restrict__ cntq) {
    const int blk = blockIdx.x;        // BC*4 blocks
    const int slice = blk >> 2;
    const int q = blk & 3;
    const float* __restrict__ hm = heat + (size_t)slice * (HH * WW);
    const int tid = threadIdx.x;
    const int lane = tid & 63;
    const int x0 = lane * 4;
    const int y0 = q * 64 + (tid >> 6) * 16;     // wave stripe: rows [y0, y0+16)
    const float NEG = -INFINITY;
    const float4 NEG4 = make_float4(NEG, NEG, NEG, NEG);

    __shared__ u64 cl[CAPQ];
    __shared__ int lcnt;
    if (tid == 0) lcnt = 0;
    __syncthreads();

    auto hmaxs = [&](const float4& v, float4& h) {
        float l = __shfl_up(v.w, 1u, 64);
        float r = __shfl_down(v.x, 1u, 64);
        if (lane == 0) l = NEG;
        if (lane == 63) r = NEG;
        h.x = fmaxf(fmaxf(l, v.x), v.y);
        h.y = fmaxf(fmaxf(v.x, v.y), v.z);
        h.z = fmaxf(fmaxf(v.y, v.z), v.w);
        h.w = fmaxf(fmaxf(v.z, v.w), r);
    };

    // ---- batch-issue all 18 row loads (rows y0-1 .. y0+16), clamped addresses ----
    float4 r[18];
    #pragma unroll
    for (int j = 0; j < 18; ++j) {
        int y = y0 - 1 + j;
        y = (y < 0) ? 0 : ((y > HH - 1) ? HH - 1 : y);   // always in-bounds: load unconditional
        r[j] = *reinterpret_cast<const float4*>(hm + y * WW + x0);
    }
    __builtin_amdgcn_sched_barrier(0);   // pin: no sinking loads into the consume loop
    // wave-uniform boundary fixup (clamped rows must act as -inf)
    if (y0 == 0)       r[0]  = NEG4;
    if (y0 + 16 == HH) r[17] = NEG4;

    // ---- rolling 3-row window out of registers ----
    float4 h0, h1, h2;
    hmaxs(r[0], h0);
    hmaxs(r[1], h1);
    #pragma unroll
    for (int t = 0; t < 16; ++t) {
        hmaxs(r[t + 2], h2);
        const float4 c = r[t + 1];
        const float va0 = fmaxf(fmaxf(h0.x, h1.x), h2.x);
        const float va1 = fmaxf(fmaxf(h0.y, h1.y), h2.y);
        const float va2 = fmaxf(fmaxf(h0.z, h1.z), h2.z);
        const float va3 = fmaxf(fmaxf(h0.w, h1.w), h2.w);
        const int ib = (y0 + t) * WW + x0;
        #define PUSH(cv, va, off)                                                       \
            if ((cv) == (va) && (cv) >= STATIC_T) {                                     \
                int p = atomicAdd(&lcnt, 1);                                            \
                if (p < CAPQ)                                                           \
                    cl[p] = ((u64)__float_as_uint(cv) << 32) |                          \
                            (u64)(0xFFFFu - (unsigned)(ib + (off)));                    \
            }
        PUSH(c.x, va0, 0)
        PUSH(c.y, va1, 1)
        PUSH(c.z, va2, 2)
        PUSH(c.w, va3, 3)
        #undef PUSH
        h0 = h1; h1 = h2;
    }
    __syncthreads();

    // coalesced flush: count + candidate list (plain stores, no global atomics)
    const int n = lcnt;
    if (tid == 0) cntq[blk] = n;
    const int nf = min(n, CAPQ);
    for (int i = tid; i < nf; i += 256) cand[(size_t)blk * CAPQ + i] = cl[i];
}

// ---------------- Kernel 2: per-slice top-30 selection (1 wave/slice) ----------------
__global__ __launch_bounds__(64, 8) void select_topk(const float* __restrict__ heat,
                                                     const u64* __restrict__ cand,
                                                     const int* __restrict__ cntq,
                                                     float* __restrict__ out, int BC) {
    const int slice = blockIdx.x;
    const int lane = threadIdx.x;
    const float NEG = -INFINITY;
    const float4 NEG4 = make_float4(NEG, NEG, NEG, NEG);

    __shared__ unsigned hist[NBINS];
    __shared__ u64 c2[CAP2];
    __shared__ int cnt2_s;
    __shared__ unsigned tb_s;

    const int n0 = cntq[slice * 4 + 0];
    const int n1 = cntq[slice * 4 + 1];
    const int n2 = cntq[slice * 4 + 2];
    const int n3 = cntq[slice * 4 + 3];
    const bool ok = (n0 <= CAPQ) && (n1 <= CAPQ) && (n2 <= CAPQ) && (n3 <= CAPQ) &&
                    (n0 + n1 + n2 + n3 >= TOPK);

    u64 loc[8];
    #pragma unroll
    for (int j = 0; j < 8; ++j) loc[j] = 0ull;

    if (ok) {
        // happy path: all peaks >= STATIC_T are in the 4 quarter lists; >= 30 total
        const int nq[4] = {n0, n1, n2, n3};
        #pragma unroll
        for (int qq = 0; qq < 4; ++qq) {
            const u64* src = cand + (size_t)(slice * 4 + qq) * CAPQ;
            if (lane < nq[qq])      loc[2 * qq]     = src[lane];
            if (lane + 64 < nq[qq]) loc[2 * qq + 1] = src[lane + 64];
        }
    } else {
        // exact fallback (never taken for this distribution): full-slice 2-pass histogram
        const float* __restrict__ hm = heat + (size_t)slice * (HH * WW);
        const int x0 = lane * 4;
        auto ld = [&](int y) { return *reinterpret_cast<const float4*>(hm + y * WW + x0); };
        auto hmaxs = [&](const float4& v, float4& h) {
            float l = __shfl_up(v.w, 1u, 64);
            float r = __shfl_down(v.x, 1u, 64);
            if (lane == 0) l = NEG;
            if (lane == 63) r = NEG;
            h.x = fmaxf(fmaxf(l, v.x), v.y);
            h.y = fmaxf(fmaxf(v.x, v.y), v.z);
            h.z = fmaxf(fmaxf(v.y, v.z), v.w);
            h.w = fmaxf(fmaxf(v.z, v.w), r);
        };
        for (int i = lane; i < NBINS; i += 64) hist[i] = 0u;
        if (lane == 0) cnt2_s = 0;
        __syncthreads();
        {
            float4 hmA = NEG4, hmB, cB, vN;
            cB = ld(0); hmaxs(cB, hmB);
            vN = ld(1);
            for (int y = 0; y < HH; ++y) {
                float4 hmC; hmaxs(vN, hmC);
                const float4 vNN = (y + 2 < HH) ? ld(y + 2) : NEG4;
                const float va0 = fmaxf(fmaxf(hmA.x, hmB.x), hmC.x);
                const float va1 = fmaxf(fmaxf(hmA.y, hmB.y), hmC.y);
                const float va2 = fmaxf(fmaxf(hmA.z, hmB.z), hmC.z);
                const float va3 = fmaxf(fmaxf(hmA.w, hmB.w), hmC.w);
                if (cB.x == va0 && cB.x > HEAT_THRESH) atomicAdd(&hist[(__float_as_uint(cB.x) - BASEBITS) >> BINSH], 1u);
                if (cB.y == va1 && cB.y > HEAT_THRESH) atomicAdd(&hist[(__float_as_uint(cB.y) - BASEBITS) >> BINSH], 1u);
                if (cB.z == va2 && cB.z > HEAT_THRESH) atomicAdd(&hist[(__float_as_uint(cB.z) - BASEBITS) >> BINSH], 1u);
                if (cB.w == va3 && cB.w > HEAT_THRESH) atomicAdd(&hist[(__float_as_uint(cB.w) - BASEBITS) >> BINSH], 1u);
                hmA = hmB; hmB = hmC; cB = vN; vN = vNN;
            }
        }
        __syncthreads();
        if (lane == 0) {
            unsigned cum = 0; int b;
            for (b = MAXBIN; b >= 0; --b) { cum += hist[b]; if (cum >= TOPK) break; }
            if (b < 0) b = 0;
            tb_s = BASEBITS + ((unsigned)b << BINSH);
        }
        __syncthreads();
        const unsigned tb = tb_s;
        {
            float4 hmA = NEG4, hmB, cB, vN;
            cB = ld(0); hmaxs(cB, hmB);
            vN = ld(1);
            for (int y = 0; y < HH; ++y) {
                float4 hmC; hmaxs(vN, hmC);
                const float4 vNN = (y + 2 < HH) ? ld(y + 2) : NEG4;
                const float va0 = fmaxf(fmaxf(hmA.x, hmB.x), hmC.x);
                const float va1 = fmaxf(fmaxf(hmA.y, hmB.y), hmC.y);
                const float va2 = fmaxf(fmaxf(hmA.z, hmB.z), hmC.z);
                const float va3 = fmaxf(fmaxf(hmA.w, hmB.w), hmC.w);
                const int ib = y * WW + x0;
                #define PUSHF(c, va, off)                                                   \
                    if ((c) == (va) && (c) > HEAT_THRESH && __float_as_uint(c) >= tb) {     \
                        int p = atomicAdd(&cnt2_s, 1);                                      \
                        if (p < CAP2)                                                       \
                            c2[p] = ((u64)__float_as_uint(c) << 32) |                       \
                                    (u64)(0xFFFFu - (unsigned)(ib + (off)));                \
                    }
                PUSHF(cB.x, va0, 0)
                PUSHF(cB.y, va1, 1)
                PUSHF(cB.z, va2, 2)
                PUSHF(cB.w, va3, 3)
                #undef PUSHF
                hmA = hmB; hmB = hmC; cB = vN; vN = vNN;
            }
        }
        __syncthreads();
        const int nn = min(cnt2_s, CAP2);
        #pragma unroll
        for (int j = 0; j < 8; ++j) {
            const int i = lane + 64 * j;
            if (i < nn) loc[j] = c2[i];
        }
    }

    // ---- top-30 via butterfly argmax over per-lane registers ----
    u64 lmax = 0ull;
    #pragma unroll
    for (int j = 0; j < 8; ++j) lmax = umax64(lmax, loc[j]);

    for (int k = 0; k < TOPK; ++k) {
        u64 wm = lmax;
        #pragma unroll
        for (int s = 32; s; s >>= 1)
            wm = umax64(wm, (u64)__shfl_xor((long long)wm, s, 64));
        if (lane == 0) {
            const size_t bk = (size_t)slice * TOPK + k;
            const size_t nbk = (size_t)BC * TOPK;
            if (wm != 0ull) {
                const unsigned fb = (unsigned)(wm >> 32);
                const unsigned idx = 0xFFFFu - (unsigned)(wm & 0xFFFFFFFFull);
                out[bk * 2]       = (float)((idx & 255) * 4);
                out[bk * 2 + 1]   = (float)((idx >> 8) * 4);
                out[nbk * 2 + bk] = __uint_as_float(fb);
                out[nbk * 3 + bk] = 1.0f;
            } else {
                out[bk * 2] = 0.0f; out[bk * 2 + 1] = 0.0f;
                out[nbk * 2 + bk] = 0.0f; out[nbk * 3 + bk] = 0.0f;
            }
        }
        if (wm != 0ull && lmax == wm) {
            u64 nl = 0ull;
            #pragma unroll
            for (int j = 0; j < 8; ++j) {
                if (loc[j] == wm) loc[j] = 0ull;
                nl = umax64(nl, loc[j]);
            }
            lmax = nl;
        }
    }
}

extern "C" void kernel_launch(void* const* d_in, const int* in_sizes, int n_in,
                              void* d_out, int out_size, void* d_ws, size_t ws_size,
                              hipStream_t stream) {
    const float* heat = (const float*)d_in[0];
    float* out = (float*)d_out;
    const int BC = in_sizes[0] / (HH * WW);
    u64* cand = (u64*)d_ws;
    int* cntq = (int*)((char*)d_ws + (size_t)BC * 4 * CAPQ * sizeof(u64));
    hipLaunchKernelGGL(nms_scan, dim3(BC * 4), dim3(256), 0, stream, heat, cand, cntq);
    hipLaunchKernelGGL(select_topk, dim3(BC), dim3(64), 0, stream, heat, cand, cntq, out, BC);
}